// Round 13
// baseline (718.170 us; speedup 1.0000x reference)
//
#include <hip/hip_runtime.h>
#include <hip/hip_bf16.h>

// MultiLoRALinear: out = x@W.T + bias + (x @ A[idx]) @ B[idx]
// M=16384, K=4096, N=4096, rank 16.
//
// R13 = R11/R12 structure at 2x occupancy (the measured deficit):
//  - 1024 threads, 16 waves @ 64x64 wave-tile (acc 4x4 f32x4 = 64 regs).
//    4 waves/SIMD (was 2) hides lgkm/vmcnt/barrier skew; __launch_bounds__
//    (1024,4) caps VGPR at 128.
//  - Same 256x256 block tile, BK=32, ring-4 LDS (128KiB), 1 barrier +
//    counted vmcnt(4) per tile (2 gloads/stage now).
//  - Epilogue: inter/B[slot]/bias staged into the freed LDS ring; per-use
//    ds_reads + per-nf memory clobber keep liveness ~110 regs (no R6 hoist).
// Tripwire: WRITE_SIZE > 350MB => spilled => revert geometry.

#define M_TOT 16384
#define K_TOT 4096
#define N_TOT 4096
#define RANK 16
#define NT 128   // K_TOT / 32

typedef __attribute__((ext_vector_type(8))) short bf16x8;
typedef __attribute__((ext_vector_type(4))) float f32x4;

// ---------------- fp32 -> bf16 (round-to-nearest-even) ----------------
__device__ __forceinline__ unsigned short f2bf(float f) {
  unsigned int u = __builtin_bit_cast(unsigned int, f);
  u += 0x7fffu + ((u >> 16) & 1u);
  return (unsigned short)(u >> 16);
}

__global__ void cvt_bf16_kernel(const float* __restrict__ src,
                                unsigned short* __restrict__ dst, int n4) {
  int i = blockIdx.x * blockDim.x + threadIdx.x;
  const int stride = gridDim.x * blockDim.x;
  for (; i < n4; i += stride) {
    const float4 v = reinterpret_cast<const float4*>(src)[i];
    ushort4 o;
    o.x = f2bf(v.x); o.y = f2bf(v.y); o.z = f2bf(v.z); o.w = f2bf(v.w);
    reinterpret_cast<ushort4*>(dst)[i] = o;
  }
}

// ------------- inter = x @ A[slot] via MFMA (wave: 16 rows x r16) -------------
__global__ __launch_bounds__(256) void lora_inter_mfma_kernel(
    const unsigned short* __restrict__ xb,
    const float* __restrict__ loraA,
    const int* __restrict__ idx,
    float* __restrict__ inter) {
  const int lane = threadIdx.x & 63;
  const int wv = threadIdx.x >> 6;
  const int m0 = blockIdx.x * 64 + wv * 16;
  const int slot = idx[m0 >> 11];
  const int q = lane >> 4;
  const int c = lane & 15;
  const unsigned short* __restrict__ xrow = xb + (size_t)(m0 + c) * K_TOT + q * 8;
  const float* __restrict__ Abase = loraA + (size_t)slot * K_TOT * RANK + c;

  f32x4 acc = (f32x4){0.f, 0.f, 0.f, 0.f};
#pragma unroll 4
  for (int kt = 0; kt < K_TOT; kt += 32) {
    const bf16x8 af = *reinterpret_cast<const bf16x8*>(xrow + kt);
    const float* __restrict__ Ak = Abase + (size_t)(kt + q * 8) * RANK;
    bf16x8 bfr;
#pragma unroll
    for (int j = 0; j < 8; ++j) bfr[j] = (short)f2bf(Ak[(size_t)j * RANK]);
    acc = __builtin_amdgcn_mfma_f32_16x16x32_bf16(af, bfr, acc, 0, 0, 0);
  }
#pragma unroll
  for (int i = 0; i < 4; ++i)
    inter[(size_t)(m0 + q * 4 + i) * RANK + c] = acc[i];
}

// ---------------- deep-pipelined 256x256 GEMM, 16 waves ----------------
__device__ __forceinline__ void gload16(const void* g, void* l) {
  __builtin_amdgcn_global_load_lds(
      (const __attribute__((address_space(1))) unsigned int*)g,
      (__attribute__((address_space(3))) unsigned int*)l, 16, 0, 0);
}

#define GBARRIER() asm volatile("s_barrier" ::: "memory")

__global__ __launch_bounds__(1024, 4) void gemm_fused_kernel(
    const unsigned short* __restrict__ xb,   // [M][K] bf16
    const unsigned short* __restrict__ wb,   // [N][K] bf16
    const float* __restrict__ bias,          // [N]
    const float* __restrict__ inter,         // [M][RANK] f32
    const float* __restrict__ loraB,         // [32][RANK][N] f32
    const int* __restrict__ idx,             // [8]
    float* __restrict__ out) {               // [M][N] f32
  // ring-4 x (A: 256x32 bf16 = 16KB, B: 16KB) = 128 KiB
  __shared__ unsigned short lds[4][16384];
  char* ldsB = (char*)&lds[0][0];

  const int tid = threadIdx.x;
  const int lane = tid & 63;
  const int wv = tid >> 6;   // 0..15
  const int wr = wv >> 2;    // 0..3 (M quarter)
  const int wc = wv & 3;     // 0..3 (N quarter)

  // XCD-aware bijective swizzle: 1024 wgs, 8 XCDs, 128 per chunk
  const int bid = ((blockIdx.x & 7) << 7) | (blockIdx.x >> 3);
  const int m0 = (bid >> 4) << 8;   // 64 M-panels
  const int n0 = (bid & 15) << 8;   // 16 N-panels

  // ---- staging source (pre-permuted by the LDS swizzle involution) ----
  const int srow = tid >> 2;                        // 0..255
  const int sslot = (tid & 3) ^ ((srow >> 1) & 3);  // 16B slot within 64B row
  const unsigned short* xsrc = xb + (size_t)(m0 + srow) * K_TOT + sslot * 8;
  const unsigned short* wsrc = wb + (size_t)(n0 + srow) * K_TOT + sslot * 8;
  const int stgoff = wv << 10;  // tid*16 = wv*1024 + lane*16

#define STAGE_T(t)                                                  \
  do {                                                              \
    const int _bo = (((t) & 3) << 15);                              \
    gload16(xsrc + (size_t)(t) * 32, ldsB + _bo + stgoff);          \
    gload16(wsrc + (size_t)(t) * 32, ldsB + _bo + 16384 + stgoff);  \
  } while (0)

  // ---- ds_read byte offsets (swizzled: phys_slot = slot ^ ((row>>1)&3)) ----
  const int rl = lane & 15;
  const int q = lane >> 4;
  const int pslot = ((q ^ ((rl >> 1) & 3)) << 4);
  const int aoff = (wr * 64 + rl) * 64 + pslot;            // + mf*1024
  const int boff = 16384 + (wc * 64 + rl) * 64 + pslot;    // + nf*1024

  f32x4 acc[4][4];
#pragma unroll
  for (int i = 0; i < 4; ++i)
#pragma unroll
    for (int j = 0; j < 4; ++j) acc[i][j] = (f32x4){0.f, 0.f, 0.f, 0.f};

  // ---- prologue: stage tiles 0,1,2 (6 loads); tile0 = 2 oldest ----
  STAGE_T(0); STAGE_T(1); STAGE_T(2);
  asm volatile("s_waitcnt vmcnt(4)" ::: "memory");
  GBARRIER();

#pragma unroll 1
  for (int t = 0; t < NT; ++t) {
    const char* Ab = ldsB + ((t & 3) << 15) + aoff;
    const char* Bb = ldsB + ((t & 3) << 15) + boff;

    bf16x8 afrag[4], bfrag[4];
#pragma unroll
    for (int nf = 0; nf < 4; ++nf)
      bfrag[nf] = *reinterpret_cast<const bf16x8*>(Bb + nf * 1024);
#pragma unroll
    for (int mf = 0; mf < 4; ++mf)
      afrag[mf] = *reinterpret_cast<const bf16x8*>(Ab + mf * 1024);
    if (t < NT - 3) STAGE_T(t + 3);

    asm volatile("s_waitcnt lgkmcnt(0)" ::: "memory");
    __builtin_amdgcn_sched_barrier(0);
    __builtin_amdgcn_s_setprio(1);
#pragma unroll
    for (int mf = 0; mf < 4; ++mf)
#pragma unroll
      for (int nf = 0; nf < 4; ++nf)
        acc[mf][nf] = __builtin_amdgcn_mfma_f32_16x16x32_bf16(
            afrag[mf], bfrag[nf], acc[mf][nf], 0, 0, 0);
    __builtin_amdgcn_s_setprio(0);
    __builtin_amdgcn_sched_barrier(0);  // frag lifetimes end inside tile t

    // boundary: stage(t+1) must be retired for all waves after barrier
    if (t <= NT - 4) {
      asm volatile("s_waitcnt vmcnt(4)" ::: "memory");
    } else if (t == NT - 3) {
      asm volatile("s_waitcnt vmcnt(2)" ::: "memory");
    } else {
      asm volatile("s_waitcnt vmcnt(0)" ::: "memory");
    }
    GBARRIER();
  }

  // ---- epilogue staging: inter / B[slot] panel / bias -> freed LDS ring ----
  const int slot = idx[m0 >> 11];
  const float* __restrict__ Bmat = loraB + (size_t)slot * RANK * N_TOT;
  {
    // interLds [256][16] f32 @ 0 (16KB): chunk tid -> row=tid>>2, part=tid&3
    const int irow = tid >> 2, ipart = tid & 3;
    gload16(inter + (size_t)(m0 + irow) * RANK + ipart * 4, ldsB + tid * 16);
    // bmatLds [16][256] f32 @ 16384 (16KB): p=tid>>6, part=tid&63
    const int p = tid >> 6, bpart = tid & 63;
    gload16(Bmat + (size_t)p * N_TOT + n0 + bpart * 4,
            ldsB + 16384 + p * 1024 + bpart * 16);
    // biasLds [256] f32 @ 32768 (1KB): wave 0 only
    if (wv == 0) gload16(bias + n0 + lane * 4, ldsB + 32768 + lane * 16);
  }
  asm volatile("s_waitcnt vmcnt(0)" ::: "memory");
  GBARRIER();

  // ---- epilogue: out = acc + bias + inter @ B[slot] (low-liveness) ----
#pragma unroll
  for (int nf = 0; nf < 4; ++nf) {
    const int col = wc * 64 + nf * 16 + rl;
    const int gn = n0 + col;
    const float bv = *reinterpret_cast<const float*>(ldsB + 32768 + col * 4);
    float bcv[RANK];
#pragma unroll
    for (int p = 0; p < RANK; ++p)
      bcv[p] = *reinterpret_cast<const float*>(ldsB + 16384 + p * 1024 + col * 4);
#pragma unroll
    for (int mf = 0; mf < 4; ++mf) {
#pragma unroll
      for (int r = 0; r < 4; ++r) {
        const int row = wr * 64 + mf * 16 + (q << 2) + r;
        const char* iRow = ldsB + row * 64;
        const float4 iv0 = *reinterpret_cast<const float4*>(iRow);
        const float4 iv1 = *reinterpret_cast<const float4*>(iRow + 16);
        const float4 iv2 = *reinterpret_cast<const float4*>(iRow + 32);
        const float4 iv3 = *reinterpret_cast<const float4*>(iRow + 48);
        const float lora =
            iv0.x * bcv[0]  + iv0.y * bcv[1]  + iv0.z * bcv[2]  + iv0.w * bcv[3] +
            iv1.x * bcv[4]  + iv1.y * bcv[5]  + iv1.z * bcv[6]  + iv1.w * bcv[7] +
            iv2.x * bcv[8]  + iv2.y * bcv[9]  + iv2.z * bcv[10] + iv2.w * bcv[11] +
            iv3.x * bcv[12] + iv3.y * bcv[13] + iv3.z * bcv[14] + iv3.w * bcv[15];
        out[(size_t)(m0 + row) * N_TOT + gn] = acc[mf][nf][r] + bv + lora;
      }
    }
    asm volatile("" ::: "memory");  // block nf-invariant iv hoist (R6 lesson)
  }
#undef STAGE_T
}

// ---------------- host launcher ----------------
extern "C" void kernel_launch(void* const* d_in, const int* in_sizes, int n_in,
                              void* d_out, int out_size, void* d_ws, size_t ws_size,
                              hipStream_t stream) {
  const float* x     = (const float*)d_in[0];  // [8,2048,4096]
  const float* w     = (const float*)d_in[1];  // [4096,4096]
  const float* bias  = (const float*)d_in[2];  // [4096]
  const float* loraA = (const float*)d_in[3];  // [32,4096,16]
  const float* loraB = (const float*)d_in[4];  // [32,16,4096]
  const int*   idx   = (const int*)d_in[5];    // [8]
  float* out = (float*)d_out;

  char* ws = (char*)d_ws;
  unsigned short* xb   = (unsigned short*)ws;                  // 134,217,728 B
  unsigned short* wbuf = (unsigned short*)(ws + 134217728);    //  33,554,432 B
  float* inter = (float*)(ws + 134217728 + 33554432);          //   1,048,576 B

  cvt_bf16_kernel<<<2048, 256, 0, stream>>>(x, xb, M_TOT * K_TOT / 4);
  cvt_bf16_kernel<<<1024, 256, 0, stream>>>(w, wbuf, N_TOT * K_TOT / 4);
  lora_inter_mfma_kernel<<<M_TOT / 64, 256, 0, stream>>>(xb, loraA, idx, inter);
  gemm_fused_kernel<<<(M_TOT / 256) * (N_TOT / 256), 1024, 0, stream>>>(
      xb, wbuf, bias, inter, loraB, idx, out);
}

// Round 14
// 705.977 us; speedup vs baseline: 1.0173x; 1.0173x over previous
//
#include <hip/hip_runtime.h>
#include <hip/hip_bf16.h>

// MultiLoRALinear: out = x@W.T + bias + (x @ A[idx]) @ B[idx]
// M=16384, K=4096, N=4096, rank 16.
//
// R14 = two independent blocks per CU (antiphase pipes), after R13 falsified
// occupancy-as-limit. Per-CU per K-step walls: MFMA 1242 cyc, LDS-frag reads
// ~1130 (96KB @85B/cyc), L2 staging ~585-857. One 128KiB block/CU phase-locks
// all waves at each barrier -> pipes alternate (measured 2500+ cyc). Fix:
//  - 256 thr / 4 waves @ 128x64 (acc[8][4], R10's proven register budget),
//    block tile 256x128, BK=32, ring-3 LDS = 72KiB -> 2 blocks/CU, whose
//    independent barriers interleave naturally.
//  - counted vmcnt(6) (6 gloads/stage, prefetch t+2), 1 barrier/tile (R11),
//    R10's epilogue verbatim. Grid 2048, XCD-swizzled (2048%8==0).
// Tripwires: VGPR<110 or WRITE>350MB => spill; MfmaUtil ~46% => antiphase
// hypothesis wrong.

#define M_TOT 16384
#define K_TOT 4096
#define N_TOT 4096
#define RANK 16
#define NT 128   // K_TOT / 32

typedef __attribute__((ext_vector_type(8))) short bf16x8;
typedef __attribute__((ext_vector_type(4))) float f32x4;

// ---------------- fp32 -> bf16 (round-to-nearest-even) ----------------
__device__ __forceinline__ unsigned short f2bf(float f) {
  unsigned int u = __builtin_bit_cast(unsigned int, f);
  u += 0x7fffu + ((u >> 16) & 1u);
  return (unsigned short)(u >> 16);
}

__global__ void cvt_bf16_kernel(const float* __restrict__ src,
                                unsigned short* __restrict__ dst, int n4) {
  int i = blockIdx.x * blockDim.x + threadIdx.x;
  const int stride = gridDim.x * blockDim.x;
  for (; i < n4; i += stride) {
    const float4 v = reinterpret_cast<const float4*>(src)[i];
    ushort4 o;
    o.x = f2bf(v.x); o.y = f2bf(v.y); o.z = f2bf(v.z); o.w = f2bf(v.w);
    reinterpret_cast<ushort4*>(dst)[i] = o;
  }
}

// ------------- inter = x @ A[slot] via MFMA (wave: 16 rows x r16) -------------
__global__ __launch_bounds__(256) void lora_inter_mfma_kernel(
    const unsigned short* __restrict__ xb,
    const float* __restrict__ loraA,
    const int* __restrict__ idx,
    float* __restrict__ inter) {
  const int lane = threadIdx.x & 63;
  const int wv = threadIdx.x >> 6;
  const int m0 = blockIdx.x * 64 + wv * 16;
  const int slot = idx[m0 >> 11];
  const int q = lane >> 4;
  const int c = lane & 15;
  const unsigned short* __restrict__ xrow = xb + (size_t)(m0 + c) * K_TOT + q * 8;
  const float* __restrict__ Abase = loraA + (size_t)slot * K_TOT * RANK + c;

  f32x4 acc = (f32x4){0.f, 0.f, 0.f, 0.f};
#pragma unroll 4
  for (int kt = 0; kt < K_TOT; kt += 32) {
    const bf16x8 af = *reinterpret_cast<const bf16x8*>(xrow + kt);
    const float* __restrict__ Ak = Abase + (size_t)(kt + q * 8) * RANK;
    bf16x8 bfr;
#pragma unroll
    for (int j = 0; j < 8; ++j) bfr[j] = (short)f2bf(Ak[(size_t)j * RANK]);
    acc = __builtin_amdgcn_mfma_f32_16x16x32_bf16(af, bfr, acc, 0, 0, 0);
  }
#pragma unroll
  for (int i = 0; i < 4; ++i)
    inter[(size_t)(m0 + q * 4 + i) * RANK + c] = acc[i];
}

// ---------------- 256x128 GEMM, 4 waves, ring-3, 2 blocks/CU ----------------
__device__ __forceinline__ void gload16(const void* g, void* l) {
  __builtin_amdgcn_global_load_lds(
      (const __attribute__((address_space(1))) unsigned int*)g,
      (__attribute__((address_space(3))) unsigned int*)l, 16, 0, 0);
}

#define GBARRIER() asm volatile("s_barrier" ::: "memory")
#define BUFSZ 24576   // A 16KB + B 8KB per ring slot

__global__ __launch_bounds__(256, 2) void gemm_fused_kernel(
    const unsigned short* __restrict__ xb,   // [M][K] bf16
    const unsigned short* __restrict__ wb,   // [N][K] bf16
    const float* __restrict__ bias,          // [N]
    const float* __restrict__ inter,         // [M][RANK] f32
    const float* __restrict__ loraB,         // [32][RANK][N] f32
    const int* __restrict__ idx,             // [8]
    float* __restrict__ out) {               // [M][N] f32
  // ring-3 x (A: 256x32 bf16 = 16KB, B: 128x32 bf16 = 8KB) = 72 KiB
  __shared__ unsigned short lds[3 * BUFSZ / 2];
  char* ldsB = (char*)lds;

  const int tid = threadIdx.x;
  const int lane = tid & 63;
  const int wv = tid >> 6;   // 0..3
  const int wr = wv >> 1;    // 0..1 (M half)
  const int wc = wv & 1;     // 0..1 (N half)

  // XCD-aware bijective swizzle: 2048 wgs, 8 XCDs, 256 per chunk
  const int bid = ((blockIdx.x & 7) << 8) | (blockIdx.x >> 3);
  const int m0 = (bid >> 5) << 8;   // 64 M-panels of 256
  const int n0 = (bid & 31) << 7;   // 32 N-panels of 128

  // ---- staging source (pre-permuted by the LDS swizzle involution) ----
  // chunk c = i*256 + tid: row = 64*i + (tid>>2), slot = tid&3 (i-invariant),
  // swz(row) = ((row>>1)&3) is also i-invariant => one base ptr per matrix.
  const int r0 = tid >> 2;
  const int scol = ((tid & 3) ^ ((r0 >> 1) & 3)) << 3;
  const unsigned short* xsrc = xb + (size_t)(m0 + r0) * K_TOT + scol;
  const unsigned short* wsrc = wb + (size_t)(n0 + r0) * K_TOT + scol;
  const int stg = tid << 4;   // linear 16B chunks

#define STAGE_T(t, bo)                                                   \
  do {                                                                   \
    const size_t _ko = (size_t)(t) * 32;                                 \
    gload16(xsrc + _ko,                       ldsB + (bo) + stg);        \
    gload16(xsrc + (size_t)64  * K_TOT + _ko, ldsB + (bo) + 4096 + stg); \
    gload16(xsrc + (size_t)128 * K_TOT + _ko, ldsB + (bo) + 8192 + stg); \
    gload16(xsrc + (size_t)192 * K_TOT + _ko, ldsB + (bo) + 12288 + stg);\
    gload16(wsrc + _ko,                       ldsB + (bo) + 16384 + stg);\
    gload16(wsrc + (size_t)64  * K_TOT + _ko, ldsB + (bo) + 20480 + stg);\
  } while (0)

  // ---- ds_read byte offsets (swizzled: phys_slot = slot ^ ((row>>1)&3)) ----
  const int rl = lane & 15;
  const int q = lane >> 4;
  const int pslot = ((q ^ ((rl >> 1) & 3)) << 4);
  const int aoff = (wr * 128 + rl) * 64 + pslot;           // + mf*1024
  const int boff = 16384 + (wc * 64 + rl) * 64 + pslot;    // + nf*1024

  f32x4 acc[8][4];
#pragma unroll
  for (int i = 0; i < 8; ++i)
#pragma unroll
    for (int j = 0; j < 4; ++j) acc[i][j] = (f32x4){0.f, 0.f, 0.f, 0.f};

  // ---- prologue: stage tiles 0,1; wait tile 0 (6 oldest of 12) ----
  STAGE_T(0, 0); STAGE_T(1, BUFSZ);
  asm volatile("s_waitcnt vmcnt(6)" ::: "memory");
  GBARRIER();

  int curoff = 0;            // (t % 3) * BUFSZ
  int stgoff3 = 2 * BUFSZ;   // ((t+2) % 3) * BUFSZ

#pragma unroll 1
  for (int t = 0; t < NT; ++t) {
    const char* Ab = ldsB + curoff + aoff;
    const char* Bb = ldsB + curoff + boff;

    bf16x8 bfrag[4], afrag[8];
#pragma unroll
    for (int nf = 0; nf < 4; ++nf)
      bfrag[nf] = *reinterpret_cast<const bf16x8*>(Bb + nf * 1024);
#pragma unroll
    for (int mf = 0; mf < 8; ++mf)
      afrag[mf] = *reinterpret_cast<const bf16x8*>(Ab + mf * 1024);
    if (t <= NT - 3) STAGE_T(t + 2, stgoff3);

    asm volatile("s_waitcnt lgkmcnt(0)" ::: "memory");
    __builtin_amdgcn_sched_barrier(0);
    __builtin_amdgcn_s_setprio(1);
#pragma unroll
    for (int mf = 0; mf < 8; ++mf)
#pragma unroll
      for (int nf = 0; nf < 4; ++nf)
        acc[mf][nf] = __builtin_amdgcn_mfma_f32_16x16x32_bf16(
            afrag[mf], bfrag[nf], acc[mf][nf], 0, 0, 0);
    __builtin_amdgcn_s_setprio(0);
    __builtin_amdgcn_sched_barrier(0);  // frag lifetimes end inside tile t

    // boundary: tile t+1 resident for all waves after this barrier
    if (t <= NT - 3) {
      asm volatile("s_waitcnt vmcnt(6)" ::: "memory");
    } else {
      asm volatile("s_waitcnt vmcnt(0)" ::: "memory");
    }
    GBARRIER();

    curoff = (curoff == 2 * BUFSZ) ? 0 : curoff + BUFSZ;
    stgoff3 = (stgoff3 == 2 * BUFSZ) ? 0 : stgoff3 + BUFSZ;
  }

  // ------------- epilogue (R10 structure): + bias + inter @ B[slot] -------------
  const int slot = idx[m0 >> 11];  // block spans one batch (256 | 2048)
  const float* __restrict__ Bmat = loraB + (size_t)slot * RANK * N_TOT;
  const int gn0 = n0 + wc * 64 + rl;

  float bcv[4][RANK];
  float bv[4];
#pragma unroll
  for (int nf = 0; nf < 4; ++nf) {
    const int gn = gn0 + nf * 16;
    bv[nf] = bias[gn];
#pragma unroll
    for (int p = 0; p < RANK; ++p) bcv[nf][p] = Bmat[(size_t)p * N_TOT + gn];
  }
#pragma unroll
  for (int mf = 0; mf < 8; ++mf) {
    const int gmb = m0 + wr * 128 + mf * 16 + (q << 2);
#pragma unroll
    for (int r = 0; r < 4; ++r) {
      const int gm = gmb + r;
      const float4* ivp = reinterpret_cast<const float4*>(inter + (size_t)gm * RANK);
      const float4 iv0 = ivp[0], iv1 = ivp[1], iv2 = ivp[2], iv3 = ivp[3];
      float* orow = out + (size_t)gm * N_TOT;
#pragma unroll
      for (int nf = 0; nf < 4; ++nf) {
        const float lora =
            iv0.x * bcv[nf][0]  + iv0.y * bcv[nf][1]  + iv0.z * bcv[nf][2]  + iv0.w * bcv[nf][3] +
            iv1.x * bcv[nf][4]  + iv1.y * bcv[nf][5]  + iv1.z * bcv[nf][6]  + iv1.w * bcv[nf][7] +
            iv2.x * bcv[nf][8]  + iv2.y * bcv[nf][9]  + iv2.z * bcv[nf][10] + iv2.w * bcv[nf][11] +
            iv3.x * bcv[nf][12] + iv3.y * bcv[nf][13] + iv3.z * bcv[nf][14] + iv3.w * bcv[nf][15];
        orow[gn0 + nf * 16] = acc[mf][nf][r] + bv[nf] + lora;
      }
    }
  }
#undef STAGE_T
}

// ---------------- host launcher ----------------
extern "C" void kernel_launch(void* const* d_in, const int* in_sizes, int n_in,
                              void* d_out, int out_size, void* d_ws, size_t ws_size,
                              hipStream_t stream) {
  const float* x     = (const float*)d_in[0];  // [8,2048,4096]
  const float* w     = (const float*)d_in[1];  // [4096,4096]
  const float* bias  = (const float*)d_in[2];  // [4096]
  const float* loraA = (const float*)d_in[3];  // [32,4096,16]
  const float* loraB = (const float*)d_in[4];  // [32,16,4096]
  const int*   idx   = (const int*)d_in[5];    // [8]
  float* out = (float*)d_out;

  char* ws = (char*)d_ws;
  unsigned short* xb   = (unsigned short*)ws;                  // 134,217,728 B
  unsigned short* wbuf = (unsigned short*)(ws + 134217728);    //  33,554,432 B
  float* inter = (float*)(ws + 134217728 + 33554432);          //   1,048,576 B

  cvt_bf16_kernel<<<2048, 256, 0, stream>>>(x, xb, M_TOT * K_TOT / 4);
  cvt_bf16_kernel<<<1024, 256, 0, stream>>>(w, wbuf, N_TOT * K_TOT / 4);
  lora_inter_mfma_kernel<<<M_TOT / 64, 256, 0, stream>>>(xb, loraA, idx, inter);
  gemm_fused_kernel<<<(M_TOT / 256) * (N_TOT / 128), 256, 0, stream>>>(
      xb, wbuf, bias, inter, loraB, idx, out);
}

// Round 15
// 643.606 us; speedup vs baseline: 1.1159x; 1.0969x over previous
//
#include <hip/hip_runtime.h>
#include <hip/hip_bf16.h>

// MultiLoRALinear: out = x@W.T + bias + (x @ A[idx]) @ B[idx]
// M=16384, K=4096, N=4096, rank 16.
//
// R15 = BK=64 dbuf-2 + counted-lgkm overlap.
// R14 falsified antiphase-via-blocks (FIFO LDS queue phase-locks blocks).
// Model: per 64-K per CU, LDS traffic 256KB (~2000-2560cyc) ~= MFMA 2484cyc;
// R11/R12 measured the SUM (5216) because lgkmcnt(0) waited whole-tile read
// batches. Fix: issue kk0 reads + kk1 B-reads up front, lgkmcnt(4) -> MFMA-1
// overlaps LDS serving B1 reads + staging writes; then A1 reads, lgkmcnt(0)
// -> MFMA-2. One barrier + vmcnt(0) per 64-K (stage issued mid-tile, ~2000cyc
// to land). Frag liveness 64 VGPR (af shared across kk, sched_barrier-pinned).
// Swizzle for 128B rows: phys_slot = slot ^ (row&7), both sides.

#define M_TOT 16384
#define K_TOT 4096
#define N_TOT 4096
#define RANK 16
#define NT2 64   // K_TOT / 64

typedef __attribute__((ext_vector_type(8))) short bf16x8;
typedef __attribute__((ext_vector_type(4))) float f32x4;

// ---------------- fp32 -> bf16 (round-to-nearest-even) ----------------
__device__ __forceinline__ unsigned short f2bf(float f) {
  unsigned int u = __builtin_bit_cast(unsigned int, f);
  u += 0x7fffu + ((u >> 16) & 1u);
  return (unsigned short)(u >> 16);
}

__global__ void cvt_bf16_kernel(const float* __restrict__ src,
                                unsigned short* __restrict__ dst, int n4) {
  int i = blockIdx.x * blockDim.x + threadIdx.x;
  const int stride = gridDim.x * blockDim.x;
  for (; i < n4; i += stride) {
    const float4 v = reinterpret_cast<const float4*>(src)[i];
    ushort4 o;
    o.x = f2bf(v.x); o.y = f2bf(v.y); o.z = f2bf(v.z); o.w = f2bf(v.w);
    reinterpret_cast<ushort4*>(dst)[i] = o;
  }
}

// ------------- inter = x @ A[slot] via MFMA (wave: 16 rows x r16) -------------
__global__ __launch_bounds__(256) void lora_inter_mfma_kernel(
    const unsigned short* __restrict__ xb,
    const float* __restrict__ loraA,
    const int* __restrict__ idx,
    float* __restrict__ inter) {
  const int lane = threadIdx.x & 63;
  const int wv = threadIdx.x >> 6;
  const int m0 = blockIdx.x * 64 + wv * 16;
  const int slot = idx[m0 >> 11];
  const int q = lane >> 4;
  const int c = lane & 15;
  const unsigned short* __restrict__ xrow = xb + (size_t)(m0 + c) * K_TOT + q * 8;
  const float* __restrict__ Abase = loraA + (size_t)slot * K_TOT * RANK + c;

  f32x4 acc = (f32x4){0.f, 0.f, 0.f, 0.f};
#pragma unroll 4
  for (int kt = 0; kt < K_TOT; kt += 32) {
    const bf16x8 af = *reinterpret_cast<const bf16x8*>(xrow + kt);
    const float* __restrict__ Ak = Abase + (size_t)(kt + q * 8) * RANK;
    bf16x8 bfr;
#pragma unroll
    for (int j = 0; j < 8; ++j) bfr[j] = (short)f2bf(Ak[(size_t)j * RANK]);
    acc = __builtin_amdgcn_mfma_f32_16x16x32_bf16(af, bfr, acc, 0, 0, 0);
  }
#pragma unroll
  for (int i = 0; i < 4; ++i)
    inter[(size_t)(m0 + q * 4 + i) * RANK + c] = acc[i];
}

// ---------------- BK=64 dbuf-2 256x256 GEMM, 8 waves ----------------
__device__ __forceinline__ void gload16(const void* g, void* l) {
  __builtin_amdgcn_global_load_lds(
      (const __attribute__((address_space(1))) unsigned int*)g,
      (__attribute__((address_space(3))) unsigned int*)l, 16, 0, 0);
}

#define GBARRIER() asm volatile("s_barrier" ::: "memory")
#define RD(p) (*reinterpret_cast<const bf16x8*>(p))

__global__ __launch_bounds__(512, 2) void gemm_fused_kernel(
    const unsigned short* __restrict__ xb,   // [M][K] bf16
    const unsigned short* __restrict__ wb,   // [N][K] bf16
    const float* __restrict__ bias,          // [N]
    const float* __restrict__ inter,         // [M][RANK] f32
    const float* __restrict__ loraB,         // [32][RANK][N] f32
    const int* __restrict__ idx,             // [8]
    float* __restrict__ out) {               // [M][N] f32
  // dbuf-2 x (A: 256x64 bf16 = 32KB @0, B: 32KB @32768) = 128 KiB
  __shared__ unsigned short lds[2][32768];
  char* ldsB = (char*)&lds[0][0];

  const int tid = threadIdx.x;
  const int lane = tid & 63;
  const int wv = tid >> 6;   // 0..7
  const int wr = wv >> 2;    // 0..1 (M half)
  const int wc = wv & 3;     // 0..3 (N quarter)

  // XCD-aware bijective swizzle: 1024 wgs, 8 XCDs, 128 per chunk
  const int bid = ((blockIdx.x & 7) << 7) | (blockIdx.x >> 3);
  const int m0 = (bid >> 4) << 8;   // 64 M-panels
  const int n0 = (bid & 15) << 8;   // 16 N-panels

  // ---- staging source (pre-permuted by the swizzle involution) ----
  // chunk c = i*512 + tid: row = i*64 + (tid>>3), slot = tid&7;
  // (row&7) = (tid>>3)&7 (i*64 === 0 mod 8) -> source col i-invariant.
  const int r0 = tid >> 3;                              // 0..63
  const int scol = ((tid & 7) ^ (r0 & 7)) << 3;         // bf16 elems
  const unsigned short* xsrc = xb + (size_t)(m0 + r0) * K_TOT + scol;
  const unsigned short* wsrc = wb + (size_t)(n0 + r0) * K_TOT + scol;
  const int stg = tid << 4;

#define STAGE64(t)                                                       \
  do {                                                                   \
    const int _bo = (((t) & 1) << 16);                                   \
    const size_t _ko = (size_t)(t) * 64;                                 \
    gload16(xsrc + _ko,                        ldsB + _bo + stg);        \
    gload16(xsrc + (size_t)64  * K_TOT + _ko,  ldsB + _bo + 8192 + stg); \
    gload16(xsrc + (size_t)128 * K_TOT + _ko,  ldsB + _bo + 16384 + stg);\
    gload16(xsrc + (size_t)192 * K_TOT + _ko,  ldsB + _bo + 24576 + stg);\
    gload16(wsrc + _ko,                        ldsB + _bo + 32768 + stg);\
    gload16(wsrc + (size_t)64  * K_TOT + _ko,  ldsB + _bo + 40960 + stg);\
    gload16(wsrc + (size_t)128 * K_TOT + _ko,  ldsB + _bo + 49152 + stg);\
    gload16(wsrc + (size_t)192 * K_TOT + _ko,  ldsB + _bo + 57344 + stg);\
  } while (0)

  // ---- ds_read byte offsets: row stride 128B, phys_slot = slot ^ (row&7) ----
  const int rl = lane & 15;
  const int q = lane >> 4;
  const int swz = rl & 7;   // (row&7) for all frag rows (multiples of 8 added)
  const int aoff0 = (wr * 128 + rl) * 128 + ((q ^ swz) << 4);          // kk0
  const int aoff1 = (wr * 128 + rl) * 128 + (((4 + q) ^ swz) << 4);    // kk1
  const int boff0 = 32768 + (wc * 64 + rl) * 128 + ((q ^ swz) << 4);
  const int boff1 = 32768 + (wc * 64 + rl) * 128 + (((4 + q) ^ swz) << 4);

  f32x4 acc[8][4];
#pragma unroll
  for (int i = 0; i < 8; ++i)
#pragma unroll
    for (int j = 0; j < 4; ++j) acc[i][j] = (f32x4){0.f, 0.f, 0.f, 0.f};

  // ---- prologue: stage tile 0, drain, barrier ----
  STAGE64(0);
  asm volatile("s_waitcnt vmcnt(0)" ::: "memory");
  GBARRIER();

#pragma unroll 1
  for (int t = 0; t < NT2; ++t) {
    const char* base = ldsB + ((t & 1) << 16);
    bf16x8 af[8], bfr0[4], bfr1[4];

    // issue kk0 reads (12) + kk1 B reads (4); then stage next tile
#pragma unroll
    for (int nf = 0; nf < 4; ++nf) bfr0[nf] = RD(base + boff0 + nf * 2048);
#pragma unroll
    for (int mf = 0; mf < 8; ++mf) af[mf] = RD(base + aoff0 + mf * 2048);
#pragma unroll
    for (int nf = 0; nf < 4; ++nf) bfr1[nf] = RD(base + boff1 + nf * 2048);
    if (t < NT2 - 1) STAGE64(t + 1);

    // wait kk0's 12 reads; bfr1's 4 stay in flight under MFMA-1
    asm volatile("s_waitcnt lgkmcnt(4)" ::: "memory");
    __builtin_amdgcn_sched_barrier(0);
    __builtin_amdgcn_s_setprio(1);
#pragma unroll
    for (int mf = 0; mf < 8; ++mf)
#pragma unroll
      for (int nf = 0; nf < 4; ++nf)
        acc[mf][nf] = __builtin_amdgcn_mfma_f32_16x16x32_bf16(
            af[mf], bfr0[nf], acc[mf][nf], 0, 0, 0);
    __builtin_amdgcn_s_setprio(0);
    __builtin_amdgcn_sched_barrier(0);  // pin: A1 reads stay below MFMA-1

    // kk1 A reads (reuse af registers; WAR resolved by fence above)
#pragma unroll
    for (int mf = 0; mf < 8; ++mf) af[mf] = RD(base + aoff1 + mf * 2048);
    asm volatile("s_waitcnt lgkmcnt(0)" ::: "memory");
    __builtin_amdgcn_sched_barrier(0);
    __builtin_amdgcn_s_setprio(1);
#pragma unroll
    for (int mf = 0; mf < 8; ++mf)
#pragma unroll
      for (int nf = 0; nf < 4; ++nf)
        acc[mf][nf] = __builtin_amdgcn_mfma_f32_16x16x32_bf16(
            af[mf], bfr1[nf], acc[mf][nf], 0, 0, 0);
    __builtin_amdgcn_s_setprio(0);
    __builtin_amdgcn_sched_barrier(0);

    // boundary: stage(t+1) (only outstanding vmem) resident for all waves
    asm volatile("s_waitcnt vmcnt(0)" ::: "memory");
    GBARRIER();
  }

  // ------------- epilogue (R10 structure): + bias + inter @ B[slot] -------------
  const int slot = idx[m0 >> 11];  // block spans one batch (256 | 2048)
  const float* __restrict__ Bmat = loraB + (size_t)slot * RANK * N_TOT;
  const int gn0 = n0 + wc * 64 + rl;

  float bcv[4][RANK];
  float bv[4];
#pragma unroll
  for (int nf = 0; nf < 4; ++nf) {
    const int gn = gn0 + nf * 16;
    bv[nf] = bias[gn];
#pragma unroll
    for (int p = 0; p < RANK; ++p) bcv[nf][p] = Bmat[(size_t)p * N_TOT + gn];
  }
#pragma unroll
  for (int mf = 0; mf < 8; ++mf) {
    const int gmb = m0 + wr * 128 + mf * 16 + (q << 2);
#pragma unroll
    for (int r = 0; r < 4; ++r) {
      const int gm = gmb + r;
      const float4* ivp = reinterpret_cast<const float4*>(inter + (size_t)gm * RANK);
      const float4 iv0 = ivp[0], iv1 = ivp[1], iv2 = ivp[2], iv3 = ivp[3];
      float* orow = out + (size_t)gm * N_TOT;
#pragma unroll
      for (int nf = 0; nf < 4; ++nf) {
        const float lora =
            iv0.x * bcv[nf][0]  + iv0.y * bcv[nf][1]  + iv0.z * bcv[nf][2]  + iv0.w * bcv[nf][3] +
            iv1.x * bcv[nf][4]  + iv1.y * bcv[nf][5]  + iv1.z * bcv[nf][6]  + iv1.w * bcv[nf][7] +
            iv2.x * bcv[nf][8]  + iv2.y * bcv[nf][9]  + iv2.z * bcv[nf][10] + iv2.w * bcv[nf][11] +
            iv3.x * bcv[nf][12] + iv3.y * bcv[nf][13] + iv3.z * bcv[nf][14] + iv3.w * bcv[nf][15];
        orow[gn0 + nf * 16] = acc[mf][nf][r] + bv[nf] + lora;
      }
    }
  }
#undef STAGE64
}

// ---------------- host launcher ----------------
extern "C" void kernel_launch(void* const* d_in, const int* in_sizes, int n_in,
                              void* d_out, int out_size, void* d_ws, size_t ws_size,
                              hipStream_t stream) {
  const float* x     = (const float*)d_in[0];  // [8,2048,4096]
  const float* w     = (const float*)d_in[1];  // [4096,4096]
  const float* bias  = (const float*)d_in[2];  // [4096]
  const float* loraA = (const float*)d_in[3];  // [32,4096,16]
  const float* loraB = (const float*)d_in[4];  // [32,16,4096]
  const int*   idx   = (const int*)d_in[5];    // [8]
  float* out = (float*)d_out;

  char* ws = (char*)d_ws;
  unsigned short* xb   = (unsigned short*)ws;                  // 134,217,728 B
  unsigned short* wbuf = (unsigned short*)(ws + 134217728);    //  33,554,432 B
  float* inter = (float*)(ws + 134217728 + 33554432);          //   1,048,576 B

  cvt_bf16_kernel<<<2048, 256, 0, stream>>>(x, xb, M_TOT * K_TOT / 4);
  cvt_bf16_kernel<<<1024, 256, 0, stream>>>(w, wbuf, N_TOT * K_TOT / 4);
  lora_inter_mfma_kernel<<<M_TOT / 64, 256, 0, stream>>>(xb, loraA, idx, inter);
  gemm_fused_kernel<<<(M_TOT / 256) * (N_TOT / 256), 512, 0, stream>>>(
      xb, wbuf, bias, inter, loraB, idx, out);
}